// Round 10
// baseline (414.342 us; speedup 1.0000x reference)
//
#include <hip/hip_runtime.h>
#include <hip/hip_bf16.h>

// WOQ int4-asym (tinygemm) linear: out[64,8192] = x @ dequant(w).T
// dequant: (q - 8)*scale + zp, groups of 128 along K.
//
// R12 = R10 + DEPTH-2 WEIGHT PIPELINE + RAW BARRIER (counted vmcnt).
// Diagnosis: R7/R10/R11's depth-1 staging makes stage_write consume the
// YOUNGEST loads -> its wait == vmcnt(0) -> every group boundary empties
// the block's HBM queue, then pays full issue+latency before data flows.
// (R11's explicit vmcnt(0) being neutral proves the drain was inherent.)
// Fix (T3/T4): never drain to 0 --
//   - wqA/wqB two-deep register staging (statically named, no runtime
//     indexing): at write time the g+2 weight loads (32KB/block) stay in
//     flight; compiler's wait at first use is vmcnt(4), not 0.
//   - issue order x(g+1), sc(g+1), wq(g+2): needed loads are all OLDER
//     than the prefetch, so ordered vmcnt never drains it.
//   - __syncthreads (emits vmcnt(0) before s_barrier) replaced with
//     asm lgkmcnt(0)+s_barrier: LDS-write visibility only; global loads
//     live across the barrier. LDS double-buffer race-audit: writes to
//     buf p in iter g are separated from iter g-1's reads of buf p by
//     the iter g-1 barrier; ds ops are issued pre/post barrier in order.
// Everything else R10 verbatim: coalesced weight staging (1KB linear per
// wave instr), dequant-on-stage to XOR-swizzled bf16 LDS, compute phase
// pure LDS+MFMA, BN=64/KSPLIT=4/512thr/2 blocks/CU, kh-pair LDS reduce +
// atomicAdd epilogue onto pre-zeroed out, nt weight loads (compiler-
// tracked so counted waits still work).

#define OUT_F 8192
#define IN_F  8192
#define M_TOK 64
#define GROUP 128
#define BN    64
#define KSPLIT 4
#define KR    (IN_F / KSPLIT)   // 2048 k per block
#define GROUPS (KR / GROUP)     // 16

typedef short short8 __attribute__((ext_vector_type(8)));
typedef float f32x4  __attribute__((ext_vector_type(4)));
typedef int   int4v  __attribute__((ext_vector_type(4)));

// lgkm-only barrier: LDS writes visible, global loads stay in flight
#define BAR() asm volatile("s_waitcnt lgkmcnt(0)\n\ts_barrier" ::: "memory")

// pack two fp32 -> packed bf16 pair (RNE, v_cvt_pk_bf16_f32)
__device__ __forceinline__ unsigned pk(float lo, float hi) {
    __hip_bfloat162 h = __float22bfloat162_rn(float2{lo, hi});
    unsigned r;
    __builtin_memcpy(&r, &h, sizeof(r));
    return r;
}

__global__ void zero_out(float* __restrict__ p) {
    const int i = (blockIdx.x * 256 + threadIdx.x) * 4;
    *(float4*)(p + i) = float4{0.f, 0.f, 0.f, 0.f};
}

__global__ __launch_bounds__(512, 4)
void woq_gemm(const float* __restrict__ x,
              const int*   __restrict__ qw,
              const float* __restrict__ sz,
              float*       __restrict__ outp) {
    // x tiles (bf16, MFMA frag order, dbuf): 2 x 16 KB
    // w tiles (bf16 [64 rows][128 k], XOR-swizzled, dbuf): 2 x 16 KB
    __shared__ int lds_x[2][4096];
    __shared__ int lds_w[2][4096];

    const int t    = threadIdx.x;       // 0..511
    const int lane = t & 63;
    const int wv   = t >> 6;            // 0..7
    const int wn   = wv & 3;            // n subtile (16 cols)
    const int kh   = wv >> 2;           // k half of each 128-group
    const int n0   = blockIdx.x * BN;
    const int k0   = blockIdx.y * KR;

    const int nlo  = lane & 15;
    const int quad = lane >> 4;
    const int row  = wn * 16 + nlo;     // tile row (n) this lane consumes
    const int n1   = n0 + row;

    // staging identities: row = i*16 + (t>>5); 16B col = t&31
    const int tr = t >> 5;              // 0..15
    const int kc = t & 31;              // 0..31

    f32x4 acc[4];
#pragma unroll
    for (int mi = 0; mi < 4; ++mi) acc[mi] = (f32x4){0.f, 0.f, 0.f, 0.f};

    int4v  wqA[4], wqB[4];   // two-deep weight staging (statically named)
    float4 xs[4];            // x stage (one group)
    float2 sc[4];            // scales (one group)

    auto issue_x = [&](int g) {
        const int kg = k0 + g * GROUP;
#pragma unroll
        for (int j = 0; j < 2; ++j) {
            const int slot  = t + 512 * j;
            const int chunk = slot >> 6;
            const int l     = slot & 63;
            const int m     = ((chunk & 3) << 4) + (l & 15);
            const int kk    = ((chunk >> 2) << 5) + ((l >> 4) << 3);
            const float4* p = (const float4*)(x + (size_t)m * IN_F + kg + kk);
            xs[2 * j]     = p[0];
            xs[2 * j + 1] = p[1];
        }
    };
    auto issue_s = [&](int g) {
        const int gg = (k0 + g * GROUP) >> 7;
#pragma unroll
        for (int i = 0; i < 4; ++i)
            sc[i] = *(const float2*)(sz + ((size_t)gg * OUT_F + n0 + i * 16 + tr) * 2);
    };
    auto issue_w = [&](int g, int4v (&wq)[4]) {
        const int kg = k0 + g * GROUP;
#pragma unroll
        for (int i = 0; i < 4; ++i)
            wq[i] = __builtin_nontemporal_load(
                (const int4v*)(qw + (size_t)(n0 + i * 16 + tr) * IN_F + kg + kc * 4));
    };
    auto write_st = [&](int buf, const int4v (&wq)[4]) {
        int* wb = lds_w[buf];
#pragma unroll
        for (int i = 0; i < 4; ++i) {
            const int r = i * 16 + tr;
            const float s = sc[i].x;
            const float c = fmaf(-8.f, sc[i].x, sc[i].y);
            int2 v;
            v.x = (int)pk(fmaf((float)wq[i].x, s, c), fmaf((float)wq[i].y, s, c));
            v.y = (int)pk(fmaf((float)wq[i].z, s, c), fmaf((float)wq[i].w, s, c));
            const int idx = (r * 64 + kc * 2) ^ ((r & 7) << 2);   // XOR swizzle
            *(int2*)&wb[idx] = v;
        }
        int* xb = lds_x[buf];
#pragma unroll
        for (int j = 0; j < 2; ++j) {
            const int slot = t + 512 * j;
            int4v bv;
            bv.x = (int)pk(xs[2 * j].x,     xs[2 * j].y);
            bv.y = (int)pk(xs[2 * j].z,     xs[2 * j].w);
            bv.z = (int)pk(xs[2 * j + 1].x, xs[2 * j + 1].y);
            bv.w = (int)pk(xs[2 * j + 1].z, xs[2 * j + 1].w);
            *(int4v*)&xb[slot * 4] = bv;
        }
    };
    auto compute = [&](const int* xb, const int* wb) {
#pragma unroll
        for (int s = 0; s < 2; ++s) {
            const int ks = kh * 2 + s;
            const int bidx = (row * 64 + ks * 16 + quad * 4) ^ ((row & 7) << 2);
            const short8 b = *(const short8*)&wb[bidx];
            short8 a[4];
#pragma unroll
            for (int mi = 0; mi < 4; ++mi)
                a[mi] = *(const short8*)&xb[((ks * 4 + mi) * 64 + lane) * 4];
#pragma unroll
            for (int mi = 0; mi < 4; ++mi)
                acc[mi] = __builtin_amdgcn_mfma_f32_16x16x32_bf16(a[mi], b, acc[mi], 0, 0, 0);
        }
    };

    // ---- prologue: stage group 0; leave wqB(1) in flight across barrier ----
    issue_x(0); issue_s(0);
    issue_w(0, wqA);
    issue_w(1, wqB);
    write_st(0, wqA);          // waits x/sc/wqA only -> wqB(1) stays in flight
    BAR();

#pragma unroll 1
    for (int k2 = 0; k2 < GROUPS / 2; ++k2) {
        const int g = 2 * k2;

        // iter A: compute g (LDS0); write g+1 (LDS1) from wqB
        issue_x(g + 1); issue_s(g + 1);
        if (k2 < GROUPS / 2 - 1) issue_w(g + 2, wqA);   // youngest: stays in flight
        compute(lds_x[0], lds_w[0]);
        write_st(1, wqB);       // vmcnt(4): wqA(g+2) still outstanding
        BAR();

        if (k2 < GROUPS / 2 - 1) {
            // iter B: compute g+1 (LDS1); write g+2 (LDS0) from wqA
            issue_x(g + 2); issue_s(g + 2);
            issue_w(g + 3, wqB);
            compute(lds_x[1], lds_w[1]);
            write_st(0, wqA);   // vmcnt(4): wqB(g+3) still outstanding
            BAR();
        } else {
            compute(lds_x[1], lds_w[1]);   // last group, nothing to stage
        }
    }

    // ---- epilogue: kh-pair reduce via LDS, then atomics ----
    __syncthreads();
    f32x4* redp = (f32x4*)&lds_x[0][0];
    if (kh == 1) {
#pragma unroll
        for (int mi = 0; mi < 4; ++mi)
            redp[(wn * 4 + mi) * 64 + lane] = acc[mi];
    }
    __syncthreads();
    if (kh == 0) {
#pragma unroll
        for (int mi = 0; mi < 4; ++mi)
            acc[mi] += redp[(wn * 4 + mi) * 64 + lane];
        // C/D layout: col = lane&15 (n), row = quad*4 + r (m within frag)
#pragma unroll
        for (int mi = 0; mi < 4; ++mi)
#pragma unroll
            for (int r = 0; r < 4; ++r)
                atomicAdd(outp + (size_t)(mi * 16 + quad * 4 + r) * OUT_F + n1, acc[mi][r]);
    }
}

extern "C" void kernel_launch(void* const* d_in, const int* in_sizes, int n_in,
                              void* d_out, int out_size, void* d_ws, size_t ws_size,
                              hipStream_t stream) {
    const float* x  = (const float*)d_in[0];
    const int*   qw = (const int*)d_in[1];
    const float* sz = (const float*)d_in[2];
    float* out = (float*)d_out;

    zero_out<<<dim3((M_TOK * OUT_F) / (256 * 4)), 256, 0, stream>>>(out);
    woq_gemm<<<dim3(OUT_F / BN, KSPLIT), 512, 0, stream>>>(x, qw, sz, out);
}

// Round 11
// 367.224 us; speedup vs baseline: 1.1283x; 1.1283x over previous
//
#include <hip/hip_runtime.h>
#include <hip/hip_bf16.h>

// WOQ int4-asym (tinygemm) linear: out[64,8192] = x @ dequant(w).T
// dequant: (q - 8)*scale + zp, groups of 128 along K.
//
// R13 = R10 VERBATIM (best measured: total 366.4us, gemm ~103us).
// R12's depth-2 counted-vmcnt pipeline regressed (+48us) -> reverted.
// Standing model: the harness's per-iteration 1-GiB d_ws poison fill
// leaves ~256MiB of dirty LLC lines that drain to DRAM DURING the gemm,
// so the gemm's effective traffic is ~512MiB (256 read + 256 writeback)
// + r/w turnaround ~= 100us — R10 sits at this contextual floor:
//   - nt weight loads (R10, +10%): avoid OUR dirty evictions;
//   - sc1 bypass (R11, neutral): the drain is the fill's data, not ours;
//   - counted vmcnt (R12, regression): drain wasn't the issue queue.
// Structure: coalesced weight staging (1KB linear per wave instr),
// dequant-on-stage to XOR-swizzled bf16 LDS, compute phase pure LDS+MFMA
// (lgkm-only), BN=64 / KSPLIT=4 / 512thr / 2 blocks/CU, one barrier per
// group, kh-pair LDS reduce + atomicAdd epilogue onto pre-zeroed out.

#define OUT_F 8192
#define IN_F  8192
#define M_TOK 64
#define GROUP 128
#define BN    64
#define KSPLIT 4
#define KR    (IN_F / KSPLIT)   // 2048 k per block
#define GROUPS (KR / GROUP)     // 16

typedef short short8 __attribute__((ext_vector_type(8)));
typedef float f32x4  __attribute__((ext_vector_type(4)));
typedef int   int4v  __attribute__((ext_vector_type(4)));

// pack two fp32 -> packed bf16 pair (RNE, v_cvt_pk_bf16_f32)
__device__ __forceinline__ unsigned pk(float lo, float hi) {
    __hip_bfloat162 h = __float22bfloat162_rn(float2{lo, hi});
    unsigned r;
    __builtin_memcpy(&r, &h, sizeof(r));
    return r;
}

__global__ void zero_out(float* __restrict__ p) {
    const int i = (blockIdx.x * 256 + threadIdx.x) * 4;
    *(float4*)(p + i) = float4{0.f, 0.f, 0.f, 0.f};
}

__global__ __launch_bounds__(512, 4)
void woq_gemm(const float* __restrict__ x,
              const int*   __restrict__ qw,
              const float* __restrict__ sz,
              float*       __restrict__ outp) {
    // x tiles (bf16, MFMA frag order, dbuf): 2 x 16 KB
    //   slot = (ks*4+mi)*64 + lane; lane l holds x[mi*16+(l&15)][ks*32+(l>>4)*8..+8]
    // w tiles (bf16 [64 rows][128 k], XOR-swizzled, dbuf): 2 x 16 KB
    __shared__ int lds_x[2][4096];
    __shared__ int lds_w[2][4096];

    const int t    = threadIdx.x;       // 0..511
    const int lane = t & 63;
    const int wv   = t >> 6;            // 0..7
    const int wn   = wv & 3;            // n subtile (16 cols)
    const int kh   = wv >> 2;           // k half of each 128-group
    const int n0   = blockIdx.x * BN;
    const int k0   = blockIdx.y * KR;

    const int nlo  = lane & 15;
    const int quad = lane >> 4;
    const int row  = wn * 16 + nlo;     // tile row (n) this lane consumes
    const int n1   = n0 + row;

    // staging identities: chunk c = i*512 + t; row = c>>5 = i*16+tr; 16B col = kc
    const int tr = t >> 5;              // 0..15
    const int kc = t & 31;              // 0..31

    f32x4 acc[4];
#pragma unroll
    for (int mi = 0; mi < 4; ++mi) acc[mi] = (f32x4){0.f, 0.f, 0.f, 0.f};

    int4v  wq[4];    // staged weights (4 rows, 16 B each, contiguous-in-row)
    float2 sc[4];    // scales for those rows
    float4 xs[4];    // staged x (2 slots x 32 B)

    auto stage_load = [&](int g) {
        const int kg = k0 + g * GROUP;
        // weights: per instr i, wave reads two full 512B row-chunks linearly.
        // NON-TEMPORAL: avoid allocating (and thus dirty-evicting) in the
        // poison-dirtied cache hierarchy.
#pragma unroll
        for (int i = 0; i < 4; ++i) {
            const int r = i * 16 + tr;
            wq[i] = __builtin_nontemporal_load(
                (const int4v*)(qw + (size_t)(n0 + r) * IN_F + kg + kc * 4));
        }
        const int gg = kg >> 7;
#pragma unroll
        for (int i = 0; i < 4; ++i) {
            const int r = i * 16 + tr;
            sc[i] = *(const float2*)(sz + ((size_t)gg * OUT_F + n0 + r) * 2);
        }
        // x tile (L2-resident, keep allocating loads for cross-block reuse)
#pragma unroll
        for (int j = 0; j < 2; ++j) {
            const int slot  = t + 512 * j;
            const int chunk = slot >> 6;
            const int l     = slot & 63;
            const int m     = ((chunk & 3) << 4) + (l & 15);
            const int kk    = ((chunk >> 2) << 5) + ((l >> 4) << 3);
            const float4* p = (const float4*)(x + (size_t)m * IN_F + kg + kk);
            xs[2 * j]     = p[0];
            xs[2 * j + 1] = p[1];
        }
    };

    auto stage_write = [&](int buf) {
        int* wb = lds_w[buf];
#pragma unroll
        for (int i = 0; i < 4; ++i) {
            const int r = i * 16 + tr;
            const float s = sc[i].x;
            const float c = fmaf(-8.f, sc[i].x, sc[i].y);
            int2 v;
            v.x = (int)pk(fmaf((float)wq[i].x, s, c), fmaf((float)wq[i].y, s, c));
            v.y = (int)pk(fmaf((float)wq[i].z, s, c), fmaf((float)wq[i].w, s, c));
            const int idx = (r * 64 + kc * 2) ^ ((r & 7) << 2);   // XOR swizzle
            *(int2*)&wb[idx] = v;
        }
        int* xb = lds_x[buf];
#pragma unroll
        for (int j = 0; j < 2; ++j) {
            const int slot = t + 512 * j;
            int4v bv;
            bv.x = (int)pk(xs[2 * j].x,     xs[2 * j].y);
            bv.y = (int)pk(xs[2 * j].z,     xs[2 * j].w);
            bv.z = (int)pk(xs[2 * j + 1].x, xs[2 * j + 1].y);
            bv.w = (int)pk(xs[2 * j + 1].z, xs[2 * j + 1].w);
            *(int4v*)&xb[slot * 4] = bv;
        }
    };

    // prologue: stage group 0
    stage_load(0);
    stage_write(0);
    __syncthreads();

    for (int g = 0; g < GROUPS; ++g) {
        if (g + 1 < GROUPS) stage_load(g + 1);   // global loads fly over compute

        // compute group g: pure LDS + MFMA (no vmcnt dependence)
        const int* xb = lds_x[g & 1];
        const int* wb = lds_w[g & 1];
#pragma unroll
        for (int s = 0; s < 2; ++s) {
            const int ks = kh * 2 + s;
            const int bidx = (row * 64 + ks * 16 + quad * 4) ^ ((row & 7) << 2);
            const short8 b = *(const short8*)&wb[bidx];
            short8 a[4];
#pragma unroll
            for (int mi = 0; mi < 4; ++mi)
                a[mi] = *(const short8*)&xb[((ks * 4 + mi) * 64 + lane) * 4];
#pragma unroll
            for (int mi = 0; mi < 4; ++mi)
                acc[mi] = __builtin_amdgcn_mfma_f32_16x16x32_bf16(a[mi], b, acc[mi], 0, 0, 0);
        }

        if (g + 1 < GROUPS) {
            stage_write((g + 1) & 1);            // waits vmcnt, writes other buf
            __syncthreads();                     // one barrier per group
        }
    }

    // ---- epilogue: kh-pair reduce via LDS, then atomics ----
    __syncthreads();
    f32x4* redp = (f32x4*)&lds_x[0][0];          // 16 KB scratch (safe: last
    if (kh == 1) {                               // compute used lds_x[1])
#pragma unroll
        for (int mi = 0; mi < 4; ++mi)
            redp[(wn * 4 + mi) * 64 + lane] = acc[mi];
    }
    __syncthreads();
    if (kh == 0) {
#pragma unroll
        for (int mi = 0; mi < 4; ++mi)
            acc[mi] += redp[(wn * 4 + mi) * 64 + lane];
        // C/D layout: col = lane&15 (n), row = quad*4 + r (m within frag)
#pragma unroll
        for (int mi = 0; mi < 4; ++mi)
#pragma unroll
            for (int r = 0; r < 4; ++r)
                atomicAdd(outp + (size_t)(mi * 16 + quad * 4 + r) * OUT_F + n1, acc[mi][r]);
    }
}

extern "C" void kernel_launch(void* const* d_in, const int* in_sizes, int n_in,
                              void* d_out, int out_size, void* d_ws, size_t ws_size,
                              hipStream_t stream) {
    const float* x  = (const float*)d_in[0];
    const int*   qw = (const int*)d_in[1];
    const float* sz = (const float*)d_in[2];
    float* out = (float*)d_out;

    zero_out<<<dim3((M_TOK * OUT_F) / (256 * 4)), 256, 0, stream>>>(out);
    woq_gemm<<<dim3(OUT_F / BN, KSPLIT), 512, 0, stream>>>(x, qw, sz, out);
}